// Round 1
// baseline (248.889 us; speedup 1.0000x reference)
//
#include <hip/hip_runtime.h>
#include <hip/hip_bf16.h>
#include <math.h>

using u16x8  = __attribute__((ext_vector_type(8))) unsigned short;
using bf16x8 = __attribute__((ext_vector_type(8))) __bf16;
using f32x4  = __attribute__((ext_vector_type(4))) float;

#define HP 66
#define C_ 256
#define K_ 2304

static __device__ __forceinline__ float bu2f(unsigned short u) {
  unsigned int v = ((unsigned int)u) << 16;
  return __builtin_bit_cast(float, v);
}
static __device__ __forceinline__ unsigned short f2bu(float f) {
  return __builtin_bit_cast(unsigned short, (__bf16)f);
}

// ---------------- Kernel 1: transpose x (B,C,H,W) fp32 -> padded channels-last bf16 (B,66,66,C)
__global__ __launch_bounds__(256) void k_transpose(const float* __restrict__ x,
                                                   unsigned short* __restrict__ xTp) {
  __shared__ float tile[64][65];
  int blk = blockIdx.x;
  int b   = blk >> 8;        // 256 blocks per image
  int rem = blk & 255;
  int cblk = rem >> 6;       // 0..3
  int h    = rem & 63;
  int c0   = cblk * 64;
  int t  = threadIdx.x;
  int tw = t & 63;
  int tg = t >> 6;           // 0..3
  const float* xb = x + (((size_t)(b * C_ + c0)) << 12) + (h << 6);
#pragma unroll
  for (int p = 0; p < 16; ++p) {
    int cl = p * 4 + tg;
    tile[cl][tw] = xb[((size_t)cl << 12) + tw];
  }
  __syncthreads();
  unsigned short* dst = xTp + (((size_t)(b * HP + h + 1)) * HP + 1) * C_ + c0;
#pragma unroll
  for (int p = 0; p < 16; ++p) {
    int wl = p * 4 + tg;
    dst[(size_t)wl * C_ + tw] = f2bu(tile[tw][wl]);
  }
}

// ---------------- Kernel 2: weight/bn prep
__global__ void k_prep(const float* __restrict__ w_dloc, const float* __restrict__ w_dcla,
                       const float* __restrict__ w_locx, const float* __restrict__ w_clax,
                       const float* __restrict__ g_loc, const float* __restrict__ be_loc,
                       const float* __restrict__ m_loc, const float* __restrict__ v_loc,
                       const float* __restrict__ g_cla, const float* __restrict__ be_cla,
                       const float* __restrict__ m_cla, const float* __restrict__ v_cla,
                       const float* __restrict__ b_locx, const float* __restrict__ b_clax,
                       unsigned short* __restrict__ wT, unsigned short* __restrict__ W2t,
                       float* __restrict__ bnA, float* __restrict__ bnB,
                       float* __restrict__ bias2) {
  int idx = blockIdx.x * blockDim.x + threadIdx.x;
  const int NWT = 512 * K_;       // 1,179,648
  const int NW2 = 80 * 512;       // 40,960
  if (idx < NWT) {
    int o  = idx / K_;
    int k  = idx - o * K_;
    int kp = k >> 8;
    int c  = k & 255;
    float v = (o < 256) ? w_dloc[(o * 256 + c) * 9 + kp]
                        : w_dcla[((o - 256) * 256 + c) * 9 + kp];
    wT[idx] = f2bu(v);
  } else if (idx < NWT + NW2) {
    int i2 = idx - NWT;
    int j  = i2 >> 9;
    int c2 = i2 & 511;
    float v = 0.f;
    if (j < 24) { if (c2 < 256) v = w_locx[j * 256 + c2]; }
    else if (j < 69) { if (c2 >= 256) v = w_clax[(j - 24) * 256 + (c2 - 256)]; }
    W2t[i2] = f2bu(v);
  } else if (idx < NWT + NW2 + 512) {
    int o = idx - NWT - NW2;
    float s, sh;
    if (o < 256) { s = g_loc[o] / sqrtf(v_loc[o] + 1e-5f); sh = be_loc[o] - m_loc[o] * s; }
    else { int o2 = o - 256; s = g_cla[o2] / sqrtf(v_cla[o2] + 1e-5f); sh = be_cla[o2] - m_cla[o2] * s; }
    bnA[o] = s; bnB[o] = sh;
  } else if (idx < NWT + NW2 + 512 + 80) {
    int j = idx - NWT - NW2 - 512;
    float v = 0.f;
    if (j < 24) v = b_locx[j];
    else if (j < 69) v = b_clax[j - 24];
    bias2[j] = v;
  }
}

// ---------------- Kernel 3: 1x1 conv for conf+offset/mask; emit gather records; write conf to out
__global__ __launch_bounds__(128) void k_offsets(const float* __restrict__ x,
    const float* __restrict__ w_om, const float* __restrict__ b_om,
    const float* __restrict__ w_conf, const float* __restrict__ b_conf,
    unsigned int* __restrict__ rec_i, float4* __restrict__ rec_w,
    float* __restrict__ out) {
  int m0 = blockIdx.x * 128;
  int b  = m0 >> 12;
  int hw = (m0 & 4095) + threadIdx.x;
  int h = hw >> 6, w = hw & 63;
  const float* xp = x + (((size_t)b) << 20) + hw;
  float acc[33];
#pragma unroll
  for (int j = 0; j < 33; ++j) acc[j] = 0.f;
  for (int c = 0; c < 256; c += 4) {
    float x0 = xp[(size_t)(c + 0) << 12];
    float x1 = xp[(size_t)(c + 1) << 12];
    float x2 = xp[(size_t)(c + 2) << 12];
    float x3 = xp[(size_t)(c + 3) << 12];
#pragma unroll
    for (int j = 0; j < 27; ++j) {
      const float4 wv = *reinterpret_cast<const float4*>(&w_om[j * 256 + c]);
      acc[j] += x0 * wv.x + x1 * wv.y + x2 * wv.z + x3 * wv.w;
    }
#pragma unroll
    for (int j = 0; j < 6; ++j) {
      const float4 wv = *reinterpret_cast<const float4*>(&w_conf[j * 256 + c]);
      acc[27 + j] += x0 * wv.x + x1 * wv.y + x2 * wv.z + x3 * wv.w;
    }
  }
#pragma unroll
  for (int j = 0; j < 6; ++j) {
    float v = acc[27 + j] + b_conf[j];
    int a = j >> 1, ch = 8 + (j & 1);
    out[(((size_t)(b * 3 + a)) * 25 + ch) * 4096 + hw] = v;
  }
  int m = m0 + (int)threadIdx.x;
#pragma unroll
  for (int k = 0; k < 9; ++k) {
    float o1 = acc[k] + b_om[k];
    float o2 = acc[9 + k] + b_om[9 + k];
    float mz = acc[18 + k] + b_om[18 + k];
    float mk = 1.f / (1.f + __expf(-mz));
    float pr = (float)(h + k / 3) + o1;   // h + PAD + (k/3 - 1)
    float pc = (float)(w + k % 3) + o2;
    pr = fminf(fmaxf(pr, 0.f), 65.f);
    pc = fminf(fmaxf(pc, 0.f), 65.f);
    int r0 = (int)floorf(pr);
    int c0 = (int)floorf(pc);
    int r1 = min(r0 + 1, 65);
    int c1 = min(c0 + 1, 65);
    float ar = 1.f + (float)r0 - pr;
    float br = 1.f - ((float)r1 - pr);
    float ac = 1.f + (float)c0 - pc;
    float bc = 1.f - ((float)c1 - pc);
    int ridx = m * 9 + k;
    rec_i[ridx] = (unsigned)r0 | ((unsigned)c0 << 8) | ((unsigned)r1 << 16) | ((unsigned)c1 << 24);
    rec_w[ridx] = make_float4(ar * ac * mk, br * bc * mk, ar * bc * mk, br * ac * mk); // lt, rb, lb, rt
  }
}

// ---------------- Kernel 4: fused gather + dual deform-conv GEMM (M=32768, N=512, K=2304) + BN + LeakyReLU
__global__ __launch_bounds__(512, 2) void k_deform_gemm(
    const unsigned short* __restrict__ xTp, const unsigned short* __restrict__ wT,
    const unsigned int* __restrict__ rec_i, const float4* __restrict__ rec_w,
    const float* __restrict__ bnA, const float* __restrict__ bnB,
    unsigned short* __restrict__ y) {
  __shared__ unsigned short Asl[128 * 72];
  __shared__ unsigned short Bsl[512 * 72];
  const int tid  = threadIdx.x;
  const int m0   = blockIdx.x * 128;
  const int b    = m0 >> 12;
  const int lane = tid & 63;
  const int wid  = tid >> 6;
  const int wm   = wid >> 2;   // 0..1
  const int wn   = wid & 3;    // 0..3
  f32x4 acc[4][8] = {};
  const unsigned short* xb = xTp + ((size_t)b) * (HP * HP * C_);

  for (int ks = 0; ks < 36; ++ks) {
    const int kp  = ks >> 2;
    const int ch0 = (ks & 3) << 6;   // 0,64,128,192
    __syncthreads();
    // stage A: 128 px x 64 ch, bilinear lerp from xTp
#pragma unroll
    for (int u = 0; u < 2; ++u) {
      int un = u * 512 + tid;
      int px = un >> 3;
      int ch = (un & 7) << 3;
      int ridx = (m0 + px) * 9 + kp;
      unsigned int ri = rec_i[ridx];
      float4 rw = rec_w[ridx];
      int r0 = ri & 255, c0v = (ri >> 8) & 255, r1 = (ri >> 16) & 255, c1v = ri >> 24;
      const unsigned short* base = xb + ch0 + ch;
      u16x8 vlt = *reinterpret_cast<const u16x8*>(base + ((r0 * 66 + c0v) << 8));
      u16x8 vrb = *reinterpret_cast<const u16x8*>(base + ((r1 * 66 + c1v) << 8));
      u16x8 vlb = *reinterpret_cast<const u16x8*>(base + ((r0 * 66 + c1v) << 8));
      u16x8 vrt = *reinterpret_cast<const u16x8*>(base + ((r1 * 66 + c0v) << 8));
      u16x8 o8;
#pragma unroll
      for (int j = 0; j < 8; ++j) {
        float v = rw.x * bu2f(vlt[j]) + rw.y * bu2f(vrb[j])
                + rw.z * bu2f(vlb[j]) + rw.w * bu2f(vrt[j]);
        o8[j] = f2bu(v);
      }
      *reinterpret_cast<u16x8*>(&Asl[px * 72 + ch]) = o8;
    }
    // stage B: 512 o x 64 ch from wT
#pragma unroll
    for (int u = 0; u < 8; ++u) {
      int un = u * 512 + tid;
      int o  = un >> 3;
      int ch = (un & 7) << 3;
      u16x8 v = *reinterpret_cast<const u16x8*>(wT + (size_t)o * K_ + (kp << 8) + ch0 + ch);
      *reinterpret_cast<u16x8*>(&Bsl[o * 72 + ch]) = v;
    }
    __syncthreads();
#pragma unroll
    for (int ksub = 0; ksub < 2; ++ksub) {
      const int kb = ksub * 32 + ((lane >> 4) << 3);
      bf16x8 af[4];
#pragma unroll
      for (int mf = 0; mf < 4; ++mf)
        af[mf] = *reinterpret_cast<const bf16x8*>(&Asl[(wm * 64 + mf * 16 + (lane & 15)) * 72 + kb]);
#pragma unroll
      for (int nf = 0; nf < 8; ++nf) {
        bf16x8 bfr = *reinterpret_cast<const bf16x8*>(&Bsl[(wn * 128 + nf * 16 + (lane & 15)) * 72 + kb]);
#pragma unroll
        for (int mf = 0; mf < 4; ++mf)
          acc[mf][nf] = __builtin_amdgcn_mfma_f32_16x16x32_bf16(af[mf], bfr, acc[mf][nf], 0, 0, 0);
      }
    }
  }
  // epilogue: BN + LeakyReLU -> y (bf16, [m][512])
#pragma unroll
  for (int nf = 0; nf < 8; ++nf) {
    int o = wn * 128 + nf * 16 + (lane & 15);
    float s = bnA[o], sh = bnB[o];
#pragma unroll
    for (int mf = 0; mf < 4; ++mf) {
#pragma unroll
      for (int j = 0; j < 4; ++j) {
        int row = wm * 64 + mf * 16 + ((lane >> 4) << 2) + j;
        float v = acc[mf][nf][j] * s + sh;
        v = (v >= 0.f) ? v : 0.01f * v;
        y[(size_t)(m0 + row) * 512 + o] = f2bu(v);
      }
    }
  }
}

// ---------------- Kernel 5: final 1x1 convs (K=512 block-diagonal, N=69) + scatter to output layout
__global__ __launch_bounds__(256) void k_final(const unsigned short* __restrict__ y,
    const unsigned short* __restrict__ W2t, const float* __restrict__ bias2,
    float* __restrict__ out) {
  __shared__ unsigned short As[64 * 40];
  __shared__ unsigned short Bs[80 * 40];
  int tid  = threadIdx.x;
  int lane = tid & 63;
  int wid  = tid >> 6;
  int m0   = blockIdx.x * 64;
  f32x4 acc[5] = {};
  for (int ksv = 0; ksv < 16; ++ksv) {
    __syncthreads();
    {
      int px = tid >> 2;
      int ch = (tid & 3) << 3;
      u16x8 v = *reinterpret_cast<const u16x8*>(y + (size_t)(m0 + px) * 512 + ksv * 32 + ch);
      *reinterpret_cast<u16x8*>(&As[px * 40 + ch]) = v;
    }
    {
      int j = tid >> 2, ch = (tid & 3) << 3;
      u16x8 v = *reinterpret_cast<const u16x8*>(W2t + (size_t)j * 512 + ksv * 32 + ch);
      *reinterpret_cast<u16x8*>(&Bs[j * 40 + ch]) = v;
      if (tid < 64) {
        int un = 256 + tid;
        int j2 = un >> 2, c2 = (un & 3) << 3;
        u16x8 v2 = *reinterpret_cast<const u16x8*>(W2t + (size_t)j2 * 512 + ksv * 32 + c2);
        *reinterpret_cast<u16x8*>(&Bs[j2 * 40 + c2]) = v2;
      }
    }
    __syncthreads();
    bf16x8 af = *reinterpret_cast<const bf16x8*>(&As[(wid * 16 + (lane & 15)) * 40 + ((lane >> 4) << 3)]);
#pragma unroll
    for (int nf = 0; nf < 5; ++nf) {
      bf16x8 bfr = *reinterpret_cast<const bf16x8*>(&Bs[(nf * 16 + (lane & 15)) * 40 + ((lane >> 4) << 3)]);
      acc[nf] = __builtin_amdgcn_mfma_f32_16x16x32_bf16(af, bfr, acc[nf], 0, 0, 0);
    }
  }
#pragma unroll
  for (int nf = 0; nf < 5; ++nf) {
    int j = nf * 16 + (lane & 15);
    if (j < 69) {
      float bs = bias2[j];
      int a, ch2;
      if (j < 24) { a = j >> 3; ch2 = j & 7; }
      else { int jj = j - 24; a = jj / 15; ch2 = 10 + (jj % 15); }
#pragma unroll
      for (int q = 0; q < 4; ++q) {
        int m  = m0 + wid * 16 + ((lane >> 4) << 2) + q;
        int bb = m >> 12, hw = m & 4095;
        out[(((size_t)(bb * 3 + a)) * 25 + ch2) * 4096 + hw] = acc[nf][q] + bs;
      }
    }
  }
}

extern "C" void kernel_launch(void* const* d_in, const int* in_sizes, int n_in,
                              void* d_out, int out_size, void* d_ws, size_t ws_size,
                              hipStream_t stream) {
  const float* x      = (const float*)d_in[0];
  const float* w_conf = (const float*)d_in[1];
  const float* b_conf = (const float*)d_in[2];
  const float* w_om   = (const float*)d_in[3];
  const float* b_om   = (const float*)d_in[4];
  const float* w_dloc = (const float*)d_in[5];
  const float* g_loc  = (const float*)d_in[6];
  const float* be_loc = (const float*)d_in[7];
  const float* m_loc  = (const float*)d_in[8];
  const float* v_loc  = (const float*)d_in[9];
  const float* w_locx = (const float*)d_in[10];
  const float* b_locx = (const float*)d_in[11];
  const float* w_dcla = (const float*)d_in[12];
  const float* g_cla  = (const float*)d_in[13];
  const float* be_cla = (const float*)d_in[14];
  const float* m_cla  = (const float*)d_in[15];
  const float* v_cla  = (const float*)d_in[16];
  const float* w_clax = (const float*)d_in[17];
  const float* b_clax = (const float*)d_in[18];
  float* out = (float*)d_out;

  char* ws = (char*)d_ws;
  size_t off = 0;
  unsigned short* xTp = (unsigned short*)(ws + off); off += (size_t)8 * HP * HP * C_ * 2;  // 17,842,176
  unsigned short* wT  = (unsigned short*)(ws + off); off += (size_t)512 * K_ * 2;          //  2,359,296
  unsigned short* W2t = (unsigned short*)(ws + off); off += (size_t)80 * 512 * 2;          //     81,920
  float* bnA   = (float*)(ws + off); off += 512 * 4;
  float* bnB   = (float*)(ws + off); off += 512 * 4;
  float* bias2 = (float*)(ws + off); off += 128 * 4;
  unsigned int* rec_i = (unsigned int*)(ws + off); off += (size_t)294912 * 4;
  float4* rec_w       = (float4*)(ws + off);       off += (size_t)294912 * 16;
  unsigned short* y   = (unsigned short*)(ws + off); off += (size_t)32768 * 512 * 2;

  hipMemsetAsync(xTp, 0, (size_t)8 * HP * HP * C_ * 2, stream);
  k_transpose<<<2048, 256, 0, stream>>>(x, xTp);
  {
    int total = 512 * K_ + 80 * 512 + 512 + 80;
    k_prep<<<(total + 255) / 256, 256, 0, stream>>>(w_dloc, w_dcla, w_locx, w_clax,
        g_loc, be_loc, m_loc, v_loc, g_cla, be_cla, m_cla, v_cla, b_locx, b_clax,
        wT, W2t, bnA, bnB, bias2);
  }
  k_offsets<<<256, 128, 0, stream>>>(x, w_om, b_om, w_conf, b_conf, rec_i, rec_w, out);
  k_deform_gemm<<<256, 512, 0, stream>>>(xTp, wT, rec_i, rec_w, bnA, bnB, y);
  k_final<<<512, 256, 0, stream>>>(y, W2t, bias2, out);
}

// Round 2
// 150.254 us; speedup vs baseline: 1.6565x; 1.6565x over previous
//
#include <hip/hip_runtime.h>
#include <hip/hip_bf16.h>
#include <math.h>

using u16x8  = __attribute__((ext_vector_type(8))) unsigned short;
using bf16x8 = __attribute__((ext_vector_type(8))) __bf16;
using f32x4  = __attribute__((ext_vector_type(4))) float;

#define HP 66
#define C_ 256
#define K_ 2304

static __device__ __forceinline__ float bu2f(unsigned short u) {
  unsigned int v = ((unsigned int)u) << 16;
  return __builtin_bit_cast(float, v);
}
static __device__ __forceinline__ unsigned short f2bu(float f) {
  return __builtin_bit_cast(unsigned short, (__bf16)f);
}
static __device__ __forceinline__ void glds16(const unsigned short* g, unsigned short* l) {
  __builtin_amdgcn_global_load_lds((const __attribute__((address_space(1))) void*)g,
                                   (__attribute__((address_space(3))) void*)l, 16, 0, 0);
}

// ---------------- Kernel 1: transpose x (B,C,H,W) fp32 -> padded channels-last bf16 (B,66,66,C)
__global__ __launch_bounds__(256) void k_transpose(const float* __restrict__ x,
                                                   unsigned short* __restrict__ xTp) {
  __shared__ float tile[64][65];
  int blk = blockIdx.x;
  int b   = blk >> 8;
  int rem = blk & 255;
  int cblk = rem >> 6;
  int h    = rem & 63;
  int c0   = cblk * 64;
  int t  = threadIdx.x;
  int tw = t & 63;
  int tg = t >> 6;
  const float* xb = x + (((size_t)(b * C_ + c0)) << 12) + (h << 6);
#pragma unroll
  for (int p = 0; p < 16; ++p) {
    int cl = p * 4 + tg;
    tile[cl][tw] = xb[((size_t)cl << 12) + tw];
  }
  __syncthreads();
  unsigned short* dst = xTp + (((size_t)(b * HP + h + 1)) * HP + 1) * C_ + c0;
#pragma unroll
  for (int p = 0; p < 16; ++p) {
    int wl = p * 4 + tg;
    dst[(size_t)wl * C_ + tw] = f2bu(tile[tw][wl]);
  }
}

// ---------------- Kernel 2: weight/bn prep (wT stored pre-swizzled for LDS slot-XOR)
__global__ void k_prep(const float* __restrict__ w_dloc, const float* __restrict__ w_dcla,
                       const float* __restrict__ w_locx, const float* __restrict__ w_clax,
                       const float* __restrict__ g_loc, const float* __restrict__ be_loc,
                       const float* __restrict__ m_loc, const float* __restrict__ v_loc,
                       const float* __restrict__ g_cla, const float* __restrict__ be_cla,
                       const float* __restrict__ m_cla, const float* __restrict__ v_cla,
                       const float* __restrict__ b_locx, const float* __restrict__ b_clax,
                       const float* __restrict__ w_om, const float* __restrict__ w_conf,
                       unsigned short* __restrict__ wT, unsigned short* __restrict__ W2t,
                       unsigned short* __restrict__ wB,
                       float* __restrict__ bnA, float* __restrict__ bnB,
                       float* __restrict__ bias2) {
  int idx = blockIdx.x * blockDim.x + threadIdx.x;
  const int NWT = 512 * K_;       // 1,179,648
  const int NW2 = 80 * 512;       // 40,960
  const int NWB = 48 * 256;       // 12,288
  if (idx < NWT) {
    int o    = idx / K_;
    int rest = idx - o * K_;
    int kp   = rest >> 8;
    int cq   = rest & 255;
    int q    = cq >> 6;
    int chp  = cq & 63;
    int sp   = chp >> 3;
    int e    = chp & 7;
    int c    = (q << 6) | ((sp ^ (o & 7)) << 3) | e;   // slot-XOR pre-swizzle
    float v = (o < 256) ? w_dloc[(o * 256 + c) * 9 + kp]
                        : w_dcla[((o - 256) * 256 + c) * 9 + kp];
    wT[idx] = f2bu(v);
  } else if (idx < NWT + NW2) {
    int i2 = idx - NWT;
    int j  = i2 >> 9;
    int c2 = i2 & 511;
    float v = 0.f;
    if (j < 24) { if (c2 < 256) v = w_locx[j * 256 + c2]; }
    else if (j < 69) { if (c2 >= 256) v = w_clax[(j - 24) * 256 + (c2 - 256)]; }
    W2t[i2] = f2bu(v);
  } else if (idx < NWT + NW2 + NWB) {
    int i3 = idx - NWT - NW2;
    int j  = i3 >> 8;
    int c  = i3 & 255;
    float v = 0.f;
    if (j < 27) v = w_om[j * 256 + c];
    else if (j < 33) v = w_conf[(j - 27) * 256 + c];
    wB[i3] = f2bu(v);
  } else if (idx < NWT + NW2 + NWB + 512) {
    int o = idx - NWT - NW2 - NWB;
    float s, sh;
    if (o < 256) { s = g_loc[o] / sqrtf(v_loc[o] + 1e-5f); sh = be_loc[o] - m_loc[o] * s; }
    else { int o2 = o - 256; s = g_cla[o2] / sqrtf(v_cla[o2] + 1e-5f); sh = be_cla[o2] - m_cla[o2] * s; }
    bnA[o] = s; bnB[o] = sh;
  } else if (idx < NWT + NW2 + NWB + 512 + 80) {
    int j = idx - NWT - NW2 - NWB - 512;
    float v = 0.f;
    if (j < 24) v = b_locx[j];
    else if (j < 69) v = b_clax[j - 24];
    bias2[j] = v;
  }
}

// ---------------- Kernel 3: MFMA 1x1 conv (M=32768,N=48,K=256) -> conf + gather records
__global__ __launch_bounds__(256) void k_offsets(const unsigned short* __restrict__ xTp,
    const unsigned short* __restrict__ wB,
    const float* __restrict__ b_om, const float* __restrict__ b_conf,
    unsigned int* __restrict__ rec_i, float4* __restrict__ rec_w,
    float* __restrict__ out) {
  __shared__ unsigned short As[128 * 40];
  __shared__ unsigned short Bs[48 * 40];
  __shared__ float P[128 * 49];
  const int tid  = threadIdx.x;
  const int lane = tid & 63;
  const int wv   = tid >> 6;
  const int m0   = blockIdx.x * 128;
  const int b    = m0 >> 12;
  f32x4 acc[2][3] = {};
  for (int ks = 0; ks < 8; ++ks) {
#pragma unroll
    for (int u = 0; u < 2; ++u) {
      int un = u * 256 + tid;
      int px = un >> 2;
      int c8 = (un & 3) << 3;
      int m  = m0 + px;
      int h  = (m & 4095) >> 6, w = m & 63;
      const unsigned short* src = xTp + (((size_t)(b * HP + h + 1)) * HP + w + 1) * C_ + ks * 32 + c8;
      *reinterpret_cast<u16x8*>(&As[px * 40 + c8]) = *reinterpret_cast<const u16x8*>(src);
    }
    if (tid < 192) {
      int j = tid >> 2, c8 = (tid & 3) << 3;
      *reinterpret_cast<u16x8*>(&Bs[j * 40 + c8]) =
          *reinterpret_cast<const u16x8*>(&wB[j * 256 + ks * 32 + c8]);
    }
    __syncthreads();
    int kb = (lane >> 4) << 3;
    bf16x8 af[2];
#pragma unroll
    for (int mf = 0; mf < 2; ++mf)
      af[mf] = *reinterpret_cast<const bf16x8*>(&As[(wv * 32 + mf * 16 + (lane & 15)) * 40 + kb]);
#pragma unroll
    for (int nf = 0; nf < 3; ++nf) {
      bf16x8 bfr = *reinterpret_cast<const bf16x8*>(&Bs[(nf * 16 + (lane & 15)) * 40 + kb]);
#pragma unroll
      for (int mf = 0; mf < 2; ++mf)
        acc[mf][nf] = __builtin_amdgcn_mfma_f32_16x16x32_bf16(af[mf], bfr, acc[mf][nf], 0, 0, 0);
    }
    __syncthreads();
  }
#pragma unroll
  for (int mf = 0; mf < 2; ++mf)
#pragma unroll
    for (int nf = 0; nf < 3; ++nf)
#pragma unroll
      for (int jj = 0; jj < 4; ++jj)
        P[(wv * 32 + mf * 16 + ((lane >> 4) << 2) + jj) * 49 + nf * 16 + (lane & 15)] = acc[mf][nf][jj];
  __syncthreads();
  if (tid < 128) {
    int px = tid;
    int m  = m0 + px;
    int hw = m & 4095;
    int h = hw >> 6, w = hw & 63;
    const float* row = &P[px * 49];
#pragma unroll
    for (int j = 0; j < 6; ++j) {
      float v = row[27 + j] + b_conf[j];
      int a = j >> 1, ch = 8 + (j & 1);
      out[(((size_t)(b * 3 + a)) * 25 + ch) * 4096 + hw] = v;
    }
#pragma unroll
    for (int k = 0; k < 9; ++k) {
      float o1 = row[k] + b_om[k];
      float o2 = row[9 + k] + b_om[9 + k];
      float mz = row[18 + k] + b_om[18 + k];
      float mk = 1.f / (1.f + __expf(-mz));
      float pr = (float)(h + k / 3) + o1;
      float pc = (float)(w + k % 3) + o2;
      pr = fminf(fmaxf(pr, 0.f), 65.f);
      pc = fminf(fmaxf(pc, 0.f), 65.f);
      int r0 = (int)floorf(pr);
      int c0 = (int)floorf(pc);
      int r1 = min(r0 + 1, 65);
      int c1 = min(c0 + 1, 65);
      float ar = 1.f + (float)r0 - pr;
      float br = 1.f - ((float)r1 - pr);
      float ac = 1.f + (float)c0 - pc;
      float bc = 1.f - ((float)c1 - pc);
      int ridx = m * 9 + k;
      rec_i[ridx] = (unsigned)r0 | ((unsigned)c0 << 8) | ((unsigned)r1 << 16) | ((unsigned)c1 << 24);
      rec_w[ridx] = make_float4(ar * ac * mk, br * bc * mk, ar * bc * mk, br * ac * mk);
    }
  }
}

// ---------------- Kernel 4: fused gather + dual deform-conv GEMM, pipelined
// A: reg-staged lerp -> swizzled ds_write (single buffer)
// B: pre-swizzled wT -> global_load_lds (double buffer), counted vmcnt
__global__ __launch_bounds__(512, 2) void k_deform_gemm(
    const unsigned short* __restrict__ xTp, const unsigned short* __restrict__ wT,
    const unsigned int* __restrict__ rec_i, const float4* __restrict__ rec_w,
    const float* __restrict__ bnA, const float* __restrict__ bnB,
    unsigned short* __restrict__ y) {
  __shared__ unsigned short Asl[128 * 64];       // 16 KB
  __shared__ unsigned short Bsl[2][512 * 64];    // 128 KB
  const int tid  = threadIdx.x;
  const int bid  = blockIdx.x;
  const int mt   = (bid & 7) * 32 + (bid >> 3);  // XCD swizzle (256 = 8*32)
  const int m0   = mt * 128;
  const int b    = m0 >> 12;
  const int lane = tid & 63;
  const int wid  = tid >> 6;
  const int wm   = wid >> 2;
  const int wn   = wid & 3;
  f32x4 acc[4][8] = {};
  const unsigned short* xb = xTp + (size_t)b * (HP * HP * C_);

  const int pxq = tid >> 3;                       // 0..63
  const int chx = (((tid & 7) ^ (pxq & 7)) << 3); // logical ch chunk this thread stages (swizzle)
  const int brow_l = lane >> 3;
  const int bsp    = lane & 7;

  float4 rw[2];
  int    off_[2][4];
  u16x8  tap[2][4];
  unsigned int ri_n[2];
  float4 rw_n[2];

  // ---- prologue: rec(kp=0), taps(0), B(0)
#pragma unroll
  for (int u = 0; u < 2; ++u) {
    int ridx = (m0 + u * 64 + pxq) * 9;
    unsigned int ri = rec_i[ridx];
    rw[u] = rec_w[ridx];
    int r0 = ri & 255, c0 = (ri >> 8) & 255, r1 = (ri >> 16) & 255, c1 = ri >> 24;
    off_[u][0] = (r0 * 66 + c0) << 8;
    off_[u][1] = (r1 * 66 + c1) << 8;
    off_[u][2] = (r0 * 66 + c1) << 8;
    off_[u][3] = (r1 * 66 + c0) << 8;
  }
#pragma unroll
  for (int u = 0; u < 2; ++u)
#pragma unroll
    for (int t = 0; t < 4; ++t)
      tap[u][t] = *reinterpret_cast<const u16x8*>(xb + off_[u][t] + chx);
  {
    const unsigned short* wsrc = wT + (size_t)(wid * 64 + brow_l) * K_ + bsp * 8;
#pragma unroll
    for (int i = 0; i < 8; ++i)
      glds16(wsrc + (size_t)i * 8 * K_, &Bsl[0][(wid * 64 + i * 8) * 64]);
  }

  for (int s = 0; s < 36; ++s) {
    const int q = s & 3;
    __builtin_amdgcn_s_barrier();             // safe to overwrite Asl / issue into Bsl[(s+1)&1]
    // ---- write phase: lerp taps(s) -> Asl (swizzled slots, conflict-free)
#pragma unroll
    for (int u = 0; u < 2; ++u) {
      u16x8 o8;
      float4 w4 = rw[u];
#pragma unroll
      for (int j = 0; j < 8; ++j) {
        float v = w4.x * bu2f(tap[u][0][j]) + w4.y * bu2f(tap[u][1][j])
                + w4.z * bu2f(tap[u][2][j]) + w4.w * bu2f(tap[u][3][j]);
        o8[j] = f2bu(v);
      }
      *reinterpret_cast<u16x8*>(&Asl[(u * 64 + pxq) * 64 + ((tid & 7) << 3)]) = o8;
    }
    // ---- prefetch phase for s+1
    if (s < 35) {
      const int sn  = s + 1;
      const int kpn = sn >> 2, qn = sn & 3;
      if (q == 0 && (s >> 2) < 8) {
#pragma unroll
        for (int u = 0; u < 2; ++u) {
          int ridx = (m0 + u * 64 + pxq) * 9 + (s >> 2) + 1;
          ri_n[u] = rec_i[ridx];
          rw_n[u] = rec_w[ridx];
        }
      }
      if (q == 3) {
#pragma unroll
        for (int u = 0; u < 2; ++u) {
          rw[u] = rw_n[u];
          unsigned int ri = ri_n[u];
          int r0 = ri & 255, c0 = (ri >> 8) & 255, r1 = (ri >> 16) & 255, c1 = ri >> 24;
          off_[u][0] = (r0 * 66 + c0) << 8;
          off_[u][1] = (r1 * 66 + c1) << 8;
          off_[u][2] = (r0 * 66 + c1) << 8;
          off_[u][3] = (r1 * 66 + c0) << 8;
        }
      }
      const unsigned short* bq = xb + (qn << 6) + chx;
#pragma unroll
      for (int u = 0; u < 2; ++u)
#pragma unroll
        for (int t = 0; t < 4; ++t)
          tap[u][t] = *reinterpret_cast<const u16x8*>(bq + off_[u][t]);
      const unsigned short* wsrc = wT + (size_t)(wid * 64 + brow_l) * K_ + kpn * 256 + qn * 64 + bsp * 8;
      unsigned short* ldst = &Bsl[sn & 1][0];
#pragma unroll
      for (int i = 0; i < 8; ++i)
        glds16(wsrc + (size_t)i * 8 * K_, ldst + (wid * 64 + i * 8) * 64);
    }
    // ---- wait: B(s) arrived (16 newer VMEM in flight: taps(s+1)+B(s+1)); A writes visible
    if (s == 35) asm volatile("s_waitcnt vmcnt(0) lgkmcnt(0)" ::: "memory");
    else         asm volatile("s_waitcnt vmcnt(16) lgkmcnt(0)" ::: "memory");
    __builtin_amdgcn_s_barrier();
    // ---- MFMA phase
    __builtin_amdgcn_s_setprio(1);
#pragma unroll
    for (int ksub = 0; ksub < 2; ++ksub) {
      const int sl = ksub * 4 + (lane >> 4);
      const int ps = (sl ^ (lane & 7)) << 3;
      bf16x8 af[4];
#pragma unroll
      for (int mf = 0; mf < 4; ++mf)
        af[mf] = *reinterpret_cast<const bf16x8*>(&Asl[(wm * 64 + mf * 16 + (lane & 15)) * 64 + ps]);
#pragma unroll
      for (int nf = 0; nf < 8; ++nf) {
        bf16x8 bfr = *reinterpret_cast<const bf16x8*>(&Bsl[s & 1][(wn * 128 + nf * 16 + (lane & 15)) * 64 + ps]);
#pragma unroll
        for (int mf = 0; mf < 4; ++mf)
          acc[mf][nf] = __builtin_amdgcn_mfma_f32_16x16x32_bf16(af[mf], bfr, acc[mf][nf], 0, 0, 0);
      }
    }
    __builtin_amdgcn_s_setprio(0);
  }
  // ---- epilogue: BN + LeakyReLU -> y (bf16, [m][512])
#pragma unroll
  for (int nf = 0; nf < 8; ++nf) {
    int o = wn * 128 + nf * 16 + (lane & 15);
    float sc = bnA[o], sh = bnB[o];
#pragma unroll
    for (int mf = 0; mf < 4; ++mf) {
#pragma unroll
      for (int j = 0; j < 4; ++j) {
        int row = wm * 64 + mf * 16 + ((lane >> 4) << 2) + j;
        float v = acc[mf][nf][j] * sc + sh;
        v = (v >= 0.f) ? v : 0.01f * v;
        y[(size_t)(m0 + row) * 512 + o] = f2bu(v);
      }
    }
  }
}

// ---------------- Kernel 5: final 1x1 convs (K=512 block-diagonal, N=69) + scatter
__global__ __launch_bounds__(256) void k_final(const unsigned short* __restrict__ y,
    const unsigned short* __restrict__ W2t, const float* __restrict__ bias2,
    float* __restrict__ out) {
  __shared__ unsigned short As[64 * 40];
  __shared__ unsigned short Bs[80 * 40];
  int tid  = threadIdx.x;
  int lane = tid & 63;
  int wid  = tid >> 6;
  int m0   = blockIdx.x * 64;
  f32x4 acc[5] = {};
  for (int ksv = 0; ksv < 16; ++ksv) {
    __syncthreads();
    {
      int px = tid >> 2;
      int ch = (tid & 3) << 3;
      u16x8 v = *reinterpret_cast<const u16x8*>(y + (size_t)(m0 + px) * 512 + ksv * 32 + ch);
      *reinterpret_cast<u16x8*>(&As[px * 40 + ch]) = v;
    }
    {
      int j = tid >> 2, ch = (tid & 3) << 3;
      u16x8 v = *reinterpret_cast<const u16x8*>(W2t + (size_t)j * 512 + ksv * 32 + ch);
      *reinterpret_cast<u16x8*>(&Bs[j * 40 + ch]) = v;
      if (tid < 64) {
        int un = 256 + tid;
        int j2 = un >> 2, c2 = (un & 3) << 3;
        u16x8 v2 = *reinterpret_cast<const u16x8*>(W2t + (size_t)j2 * 512 + ksv * 32 + c2);
        *reinterpret_cast<u16x8*>(&Bs[j2 * 40 + c2]) = v2;
      }
    }
    __syncthreads();
    bf16x8 af = *reinterpret_cast<const bf16x8*>(&As[(wid * 16 + (lane & 15)) * 40 + ((lane >> 4) << 3)]);
#pragma unroll
    for (int nf = 0; nf < 5; ++nf) {
      bf16x8 bfr = *reinterpret_cast<const bf16x8*>(&Bs[(nf * 16 + (lane & 15)) * 40 + ((lane >> 4) << 3)]);
      acc[nf] = __builtin_amdgcn_mfma_f32_16x16x32_bf16(af, bfr, acc[nf], 0, 0, 0);
    }
  }
#pragma unroll
  for (int nf = 0; nf < 5; ++nf) {
    int j = nf * 16 + (lane & 15);
    if (j < 69) {
      float bs = bias2[j];
      int a, ch2;
      if (j < 24) { a = j >> 3; ch2 = j & 7; }
      else { int jj = j - 24; a = jj / 15; ch2 = 10 + (jj % 15); }
#pragma unroll
      for (int q = 0; q < 4; ++q) {
        int m  = m0 + wid * 16 + ((lane >> 4) << 2) + q;
        int bb = m >> 12, hw = m & 4095;
        out[(((size_t)(bb * 3 + a)) * 25 + ch2) * 4096 + hw] = acc[nf][q] + bs;
      }
    }
  }
}

extern "C" void kernel_launch(void* const* d_in, const int* in_sizes, int n_in,
                              void* d_out, int out_size, void* d_ws, size_t ws_size,
                              hipStream_t stream) {
  const float* x      = (const float*)d_in[0];
  const float* w_conf = (const float*)d_in[1];
  const float* b_conf = (const float*)d_in[2];
  const float* w_om   = (const float*)d_in[3];
  const float* b_om   = (const float*)d_in[4];
  const float* w_dloc = (const float*)d_in[5];
  const float* g_loc  = (const float*)d_in[6];
  const float* be_loc = (const float*)d_in[7];
  const float* m_loc  = (const float*)d_in[8];
  const float* v_loc  = (const float*)d_in[9];
  const float* w_locx = (const float*)d_in[10];
  const float* b_locx = (const float*)d_in[11];
  const float* w_dcla = (const float*)d_in[12];
  const float* g_cla  = (const float*)d_in[13];
  const float* be_cla = (const float*)d_in[14];
  const float* m_cla  = (const float*)d_in[15];
  const float* v_cla  = (const float*)d_in[16];
  const float* w_clax = (const float*)d_in[17];
  const float* b_clax = (const float*)d_in[18];
  float* out = (float*)d_out;

  char* ws = (char*)d_ws;
  size_t off = 0;
  unsigned short* xTp = (unsigned short*)(ws + off); off += (size_t)8 * HP * HP * C_ * 2;
  unsigned short* wT  = (unsigned short*)(ws + off); off += (size_t)512 * K_ * 2;
  unsigned short* W2t = (unsigned short*)(ws + off); off += (size_t)80 * 512 * 2;
  unsigned short* wB  = (unsigned short*)(ws + off); off += (size_t)48 * 256 * 2;
  float* bnA   = (float*)(ws + off); off += 512 * 4;
  float* bnB   = (float*)(ws + off); off += 512 * 4;
  float* bias2 = (float*)(ws + off); off += 128 * 4;
  unsigned int* rec_i = (unsigned int*)(ws + off); off += (size_t)294912 * 4;
  float4* rec_w       = (float4*)(ws + off);       off += (size_t)294912 * 16;
  unsigned short* y   = (unsigned short*)(ws + off); off += (size_t)32768 * 512 * 2;

  hipMemsetAsync(xTp, 0, (size_t)8 * HP * HP * C_ * 2, stream);
  k_transpose<<<2048, 256, 0, stream>>>(x, xTp);
  {
    int total = 512 * K_ + 80 * 512 + 48 * 256 + 512 + 80;
    k_prep<<<(total + 255) / 256, 256, 0, stream>>>(w_dloc, w_dcla, w_locx, w_clax,
        g_loc, be_loc, m_loc, v_loc, g_cla, be_cla, m_cla, v_cla, b_locx, b_clax,
        w_om, w_conf, wT, W2t, wB, bnA, bnB, bias2);
  }
  k_offsets<<<256, 256, 0, stream>>>(xTp, wB, b_om, b_conf, rec_i, rec_w, out);
  k_deform_gemm<<<256, 512, 0, stream>>>(xTp, wT, rec_i, rec_w, bnA, bnB, y);
  k_final<<<512, 256, 0, stream>>>(y, W2t, bias2, out);
}